// Round 13
// baseline (544.420 us; speedup 1.0000x reference)
//
#include <hip/hip_runtime.h>
#include <hip/hip_bf16.h>
#include <hip/hip_cooperative_groups.h>
#include <limits.h>

namespace cg = cooperative_groups;

#define N_NODES 50000
#define N_EDGES 800000
#define HID 128
#define N_LAYER 3
#define FC_HID 256
#define N_CLASS 10
#define N_GRAPHS 64
#define NBKT 98                          // raw dst>>9; raw dst < 50000 -> buckets 0..97
#define BIN_NB 256                       // edge-slice blocks
#define PER_BLK ((N_EDGES + BIN_NB - 1) / BIN_NB)  // 3125
#define CVT_NB ((N_NODES * HID / 4 + 255) / 256)   // 6250

typedef __attribute__((ext_vector_type(8))) short short8;   // 8 bf16 = 4 VGPRs
typedef __attribute__((ext_vector_type(4))) float f32x4;

__device__ inline unsigned f2bf(float f) {  // RNE f32 -> bf16 bits
    unsigned u = __float_as_uint(f);
    return (u + 0x7FFFu + ((u >> 16) & 1u)) >> 16;
}
__device__ inline float bf2f(unsigned b) { return __uint_as_float(b << 16); }

__device__ inline void wprep_one(const float* __restrict__ src, unsigned* __restrict__ dh,
                                 unsigned* __restrict__ dl, int t, int per) {
    for (int i = 0; i < per; ++i) {
        int u = t * per + i;              // 0..8191: n = u>>6 (out col), kk = u&63 (k pair)
        int n = u >> 6, kk = u & 63;
        float v0 = src[(size_t)(2 * kk) * HID + n];
        float v1 = src[(size_t)(2 * kk + 1) * HID + n];
        unsigned h0 = f2bf(v0), h1 = f2bf(v1);
        unsigned l0 = f2bf(v0 - bf2f(h0)), l1 = f2bf(v1 - bf2f(h1));
        dh[u] = h0 | (h1 << 16);
        dl[u] = l0 | (l1 << 16);
    }
}

// ===================== ONE cooperative kernel: whole preprocessing chain =====================
// 256 blocks x 512 threads, co-resident (2 blocks/CU). Phases separated by grid.sync().
__global__ __launch_bounds__(512) void k_prep_all(
    const int* __restrict__ ei, const float* __restrict__ x,
    const float* __restrict__ Wl, const float* __restrict__ Wr,
    unsigned* __restrict__ xb,
    unsigned* __restrict__ wlh, unsigned* __restrict__ wll,
    unsigned* __restrict__ wrh, unsigned* __restrict__ wrl,
    float* __restrict__ pooled, int* __restrict__ bmin, int* __restrict__ hist,
    int* __restrict__ colex, int* __restrict__ btot, int* __restrict__ bboff,
    int* __restrict__ rp, int* __restrict__ emin, const int* __restrict__ batch,
    float* __restrict__ counts, unsigned* __restrict__ ebuf,
    float* __restrict__ invd, int* __restrict__ csr) {
    cg::grid_group grid = cg::this_grid();
    __shared__ int sm[1536];   // phase-wise union (max: scatter 3x512)
    const int b = blockIdx.x, t = threadIdx.x;

    // ---- phase 0 (no sync needed before phase 1 - independent buffers, no LDS) ----
    {
        int gid = b * 512 + t;
        if (gid < N_GRAPHS * HID * N_LAYER) pooled[gid] = 0.f;   // zero pooled
        for (int i = gid; i < N_NODES * HID / 4; i += BIN_NB * 512) {  // x -> bf16x2
            float4 v = *(const float4*)(x + (size_t)i * 4);
            uint2 o;
            o.x = f2bf(v.x) | (f2bf(v.y) << 16);
            o.y = f2bf(v.z) | (f2bf(v.w) << 16);
            *(uint2*)(xb + (size_t)i * 2) = o;
        }
        if (b >= 250) {  // W split-precision transpose, one matrix per block
            int w = b - 250;
            const float* src = (w < 3) ? (Wl + (size_t)w * HID * HID)
                                       : (Wr + (size_t)(w - 3) * HID * HID);
            unsigned* dh = (w < 3) ? (wlh + (size_t)w * HID * 64) : (wrh + (size_t)(w - 3) * HID * 64);
            unsigned* dl = (w < 3) ? (wll + (size_t)w * HID * 64) : (wrl + (size_t)(w - 3) * HID * 64);
            wprep_one(src, dh, dl, t, 16);
        }
    }

    // ---- phase 1: per-block edge min + per-(block,bucket) dst histogram ----
    {
        int* red = sm;        // [512]
        int* lh = sm + 512;   // [98]
        if (t < NBKT) lh[t] = 0;
        __syncthreads();
        int e0 = b * PER_BLK, e1 = min(e0 + PER_BLK, N_EDGES);
        int v = INT_MAX;
        for (int j = e0 + t; j < e1; j += 512) {
            int s = ei[j], d = ei[N_EDGES + j];
            v = min(v, min(s, d));
            atomicAdd(&lh[d >> 9], 1);
        }
        red[t] = v;
        __syncthreads();
        for (int off = 256; off > 0; off >>= 1) {
            if (t < off) red[t] = min(red[t], red[t + off]);
            __syncthreads();
        }
        if (t == 0) bmin[b] = red[0];
        if (t < NBKT) hist[b * NBKT + t] = lh[t];
    }
    __threadfence();
    grid.sync();

    // ---- phase 2: blocks 0..97: column scan over edge-slices -> colex, btot ----
    if (b < NBKT) {
        int* s = sm;  // [256]
        int v = 0;
        if (t < BIN_NB) { v = hist[t * NBKT + b]; s[t] = v; }
        __syncthreads();
        for (int off = 1; off < BIN_NB; off <<= 1) {
            int u = (t >= off && t < BIN_NB) ? s[t - off] : 0;
            __syncthreads();
            if (t < BIN_NB) s[t] += u;
            __syncthreads();
        }
        if (t < BIN_NB) colex[t * NBKT + b] = s[t] - v;
        if (t == BIN_NB - 1) btot[b] = s[t];
    }
    __threadfence();
    grid.sync();

    // ---- phase 3: block 0: emin reduce + bucket scan (bboff) + per-graph counts ----
    if (b == 0) {
        int* s = sm;          // [128]
        int* s2 = sm + 128;   // [128]
        if (t < 128) s2[t] = min(bmin[t], bmin[t + 128]);
        __syncthreads();
        for (int off = 64; off > 0; off >>= 1) {
            if (t < off) s2[t] = min(s2[t], s2[t + off]);
            __syncthreads();
        }
        if (t == 0) *emin = s2[0];
        int v = (t < NBKT) ? btot[t] : 0;
        if (t < 128) s[t] = v;
        __syncthreads();
        for (int off = 1; off < 128; off <<= 1) {
            int u = (t >= off && t < 128) ? s[t - off] : 0;
            __syncthreads();
            if (t < 128) s[t] += u;
            __syncthreads();
        }
        if (t < NBKT) bboff[t] = s[t] - v;
        if (t == 127) { bboff[NBKT] = s[127]; rp[N_NODES] = s[127]; }
        if (t < N_GRAPHS) {
            int g = t;
            int lo = 0, hi = N_NODES;
            while (lo < hi) { int mid = (lo + hi) >> 1; if (batch[mid] < g) lo = mid + 1; else hi = mid; }
            int lb = lo;
            lo = lb; hi = N_NODES;
            while (lo < hi) { int mid = (lo + hi) >> 1; if (batch[mid] <= g) lo = mid + 1; else hi = mid; }
            counts[g] = (float)(lo - lb);
        }
    }
    __threadfence();
    grid.sync();

    // ---- phase 4: bin edges -> bucket-contiguous packed ebuf ----
    {
        int* lcnt = sm;          // [98]
        int* lbase = sm + 128;   // [98]
        if (t < NBKT) {
            lcnt[t] = 0;
            lbase[t] = bboff[t] + colex[b * NBKT + t];
        }
        __syncthreads();
        int m = *emin;
        int e0 = b * PER_BLK, e1 = min(e0 + PER_BLK, N_EDGES);
        for (int j = e0 + t; j < e1; j += 512) {
            int s = ei[j] - m, d = ei[N_EDGES + j];
            int bk = d >> 9;
            int idx = atomicAdd(&lcnt[bk], 1);
            ebuf[lbase[bk] + idx] = ((unsigned)s << 9) | (unsigned)(d & 511);
        }
    }
    __threadfence();
    grid.sync();

    // ---- phase 5: blocks 0..98: per-bucket local deg/scan -> rp, invd, CSR placement ----
    if (b <= NBKT) {
        int m = *emin;
        if (b == NBKT) {  // tail guard: nodes past bucket coverage
            for (int nd = NBKT * 512 - m + t; nd < N_NODES; nd += 512)
                if (nd >= 0) { rp[nd] = N_EDGES; invd[nd] = 1.0f; }
        } else {
            int* ldeg = sm;           // [512]
            int* lsc = sm + 512;      // [512]
            int* lfill = sm + 1024;   // [512]
            ldeg[t] = 0;
            lfill[t] = 0;
            __syncthreads();
            int beg = bboff[b], end = bboff[b + 1];
            for (int e = beg + t; e < end; e += 512)
                atomicAdd(&ldeg[ebuf[e] & 511], 1);
            __syncthreads();
            int v = ldeg[t];
            lsc[t] = v;
            __syncthreads();
            for (int off = 1; off < 512; off <<= 1) {
                int u = (t >= off) ? lsc[t - off] : 0;
                __syncthreads();
                lsc[t] += u;
                __syncthreads();
            }
            int base = beg + lsc[t] - v;
            lsc[t] = base;
            int nd = (b << 9) + t - m;
            if (nd >= 0 && nd < N_NODES) {
                rp[nd] = base;
                invd[nd] = 1.0f / (float)max(v, 1);
            }
            __syncthreads();
            for (int e = beg + t; e < end; e += 512) {
                unsigned p = ebuf[e];
                int loc = p & 511;
                int pos = lsc[loc] + atomicAdd(&lfill[loc], 1);
                csr[pos] = (int)(p >> 9);
            }
        }
    }
}

// ================= discrete fallback kernels (used only if coop launch fails) =================
__global__ __launch_bounds__(512) void k_minh(const int* __restrict__ ei,
                                              int* __restrict__ bmin,
                                              int* __restrict__ hist) {
    __shared__ int red[512];
    __shared__ int lh[NBKT];
    int t = threadIdx.x;
    if (t < NBKT) lh[t] = 0;
    __syncthreads();
    int e0 = blockIdx.x * PER_BLK, e1 = min(e0 + PER_BLK, N_EDGES);
    int v = INT_MAX;
    for (int j = e0 + t; j < e1; j += 512) {
        int s = ei[j], d = ei[N_EDGES + j];
        v = min(v, min(s, d));
        atomicAdd(&lh[d >> 9], 1);
    }
    red[t] = v;
    __syncthreads();
    for (int off = 256; off > 0; off >>= 1) {
        if (t < off) red[t] = min(red[t], red[t + off]);
        __syncthreads();
    }
    if (t == 0) bmin[blockIdx.x] = red[0];
    if (t < NBKT) hist[blockIdx.x * NBKT + t] = lh[t];
}

__global__ void k_base(const int* __restrict__ hist, int* __restrict__ colex,
                       int* __restrict__ btot, float* __restrict__ pooled) {
    __shared__ int s[BIN_NB];
    int b = blockIdx.x, t = threadIdx.x;
    int gid = b * BIN_NB + t;
    if (gid < N_GRAPHS * HID * N_LAYER) pooled[gid] = 0.f;
    int v = hist[t * NBKT + b];
    s[t] = v;
    __syncthreads();
    for (int off = 1; off < BIN_NB; off <<= 1) {
        int u = (t >= off) ? s[t - off] : 0;
        __syncthreads();
        s[t] += u;
        __syncthreads();
    }
    colex[t * NBKT + b] = s[t] - v;
    if (t == BIN_NB - 1) btot[b] = s[t];
}

__global__ void k_bscan(const int* __restrict__ btot, const int* __restrict__ bmin,
                        int* __restrict__ bboff, int* __restrict__ rp,
                        int* __restrict__ emin, const int* __restrict__ batch,
                        float* __restrict__ counts) {
    __shared__ int s[128];
    __shared__ int s2[128];
    int t = threadIdx.x;
    s2[t] = min(bmin[t], bmin[t + 128]);
    __syncthreads();
    for (int off = 64; off > 0; off >>= 1) {
        if (t < off) s2[t] = min(s2[t], s2[t + off]);
        __syncthreads();
    }
    if (t == 0) *emin = s2[0];
    int v = (t < NBKT) ? btot[t] : 0;
    s[t] = v;
    __syncthreads();
    for (int off = 1; off < 128; off <<= 1) {
        int u = (t >= off) ? s[t - off] : 0;
        __syncthreads();
        s[t] += u;
        __syncthreads();
    }
    if (t < NBKT) bboff[t] = s[t] - v;
    if (t == 127) { bboff[NBKT] = s[127]; rp[N_NODES] = s[127]; }
    if (t < N_GRAPHS) {
        int g = t;
        int lo = 0, hi = N_NODES;
        while (lo < hi) { int mid = (lo + hi) >> 1; if (batch[mid] < g) lo = mid + 1; else hi = mid; }
        int lb = lo;
        lo = lb; hi = N_NODES;
        while (lo < hi) { int mid = (lo + hi) >> 1; if (batch[mid] <= g) lo = mid + 1; else hi = mid; }
        counts[g] = (float)(lo - lb);
    }
}

__global__ __launch_bounds__(512) void k_bin(const int* __restrict__ ei,
                                             const int* __restrict__ emin,
                                             const int* __restrict__ bboff,
                                             const int* __restrict__ colex,
                                             unsigned* __restrict__ ebuf) {
    __shared__ int lcnt[NBKT];
    __shared__ int lbase[NBKT];
    int t = threadIdx.x, blk = blockIdx.x;
    if (t < NBKT) {
        lcnt[t] = 0;
        lbase[t] = bboff[t] + colex[blk * NBKT + t];
    }
    __syncthreads();
    int m = *emin;
    int e0 = blk * PER_BLK, e1 = min(e0 + PER_BLK, N_EDGES);
    for (int j = e0 + t; j < e1; j += 512) {
        int s = ei[j] - m, d = ei[N_EDGES + j];
        int bk = d >> 9;
        int idx = atomicAdd(&lcnt[bk], 1);
        ebuf[lbase[bk] + idx] = ((unsigned)s << 9) | (unsigned)(d & 511);
    }
}

__global__ __launch_bounds__(512) void k_scatter2(const unsigned* __restrict__ ebuf,
                                                  const int* __restrict__ bboff,
                                                  const int* __restrict__ emin,
                                                  int* __restrict__ rp,
                                                  float* __restrict__ invd,
                                                  int* __restrict__ csr) {
    __shared__ int ldeg[512];
    __shared__ int lsc[512];
    __shared__ int lfill[512];
    int b = blockIdx.x, t = threadIdx.x;
    int m = *emin;
    if (b == NBKT) {
        for (int nd = NBKT * 512 - m + t; nd < N_NODES; nd += 512)
            if (nd >= 0) { rp[nd] = N_EDGES; invd[nd] = 1.0f; }
        return;
    }
    ldeg[t] = 0;
    lfill[t] = 0;
    __syncthreads();
    int beg = bboff[b], end = bboff[b + 1];
    for (int e = beg + t; e < end; e += 512)
        atomicAdd(&ldeg[ebuf[e] & 511], 1);
    __syncthreads();
    int v = ldeg[t];
    lsc[t] = v;
    __syncthreads();
    for (int off = 1; off < 512; off <<= 1) {
        int u = (t >= off) ? lsc[t - off] : 0;
        __syncthreads();
        lsc[t] += u;
        __syncthreads();
    }
    int base = beg + lsc[t] - v;
    lsc[t] = base;
    int nd = (b << 9) + t - m;
    if (nd >= 0 && nd < N_NODES) {
        rp[nd] = base;
        invd[nd] = 1.0f / (float)max(v, 1);
    }
    __syncthreads();
    for (int e = beg + t; e < end; e += 512) {
        unsigned p = ebuf[e];
        int loc = p & 511;
        int pos = lsc[loc] + atomicAdd(&lfill[loc], 1);
        csr[pos] = (int)(p >> 9);
    }
}

__global__ void k_cvtprep(const float* __restrict__ x, unsigned* __restrict__ xb,
                          const float* __restrict__ Wl, const float* __restrict__ Wr,
                          unsigned* __restrict__ wlh, unsigned* __restrict__ wll,
                          unsigned* __restrict__ wrh, unsigned* __restrict__ wrl) {
    int b = blockIdx.x, t = threadIdx.x;
    if (b < 6) {
        const float* src = (b < 3) ? (Wl + (size_t)b * HID * HID) : (Wr + (size_t)(b - 3) * HID * HID);
        unsigned* dh = (b < 3) ? (wlh + (size_t)b * HID * 64) : (wrh + (size_t)(b - 3) * HID * 64);
        unsigned* dl = (b < 3) ? (wll + (size_t)b * HID * 64) : (wrl + (size_t)(b - 3) * HID * 64);
        wprep_one(src, dh, dl, t, 32);
    } else {
        int i = (b - 6) * 256 + t;
        if (i < N_NODES * HID / 4) {
            float4 v = *(const float4*)(x + (size_t)i * 4);
            uint2 o;
            o.x = f2bf(v.x) | (f2bf(v.y) << 16);
            o.y = f2bf(v.z) | (f2bf(v.w) << 16);
            *(uint2*)(xb + (size_t)i * 2) = o;
        }
    }
}

// ---------------- mean aggregation: one wave per node, full 256B rows, 16-deep MLP ----------
__global__ void k_agg(const unsigned* __restrict__ hb, const int* __restrict__ rp,
                      const int* __restrict__ csr, const float* __restrict__ invd,
                      unsigned* __restrict__ aggb) {
    const int n = blockIdx.x;
    const int lane = threadIdx.x;  // 64; lane covers features 2*lane, 2*lane+1
    int beg = rp[n], end = rp[n + 1];
    float a0 = 0, a1 = 0, b0 = 0, b1 = 0, c0 = 0, c1 = 0, d0 = 0, d1 = 0;
    int e = beg;
    for (; e + 16 <= end; e += 16) {  // 16 outstanding loads: one batch covers avg degree
        int s[16];
        unsigned u[16];
#pragma unroll
        for (int i = 0; i < 16; ++i) s[i] = csr[e + i];
#pragma unroll
        for (int i = 0; i < 16; ++i) u[i] = hb[(size_t)s[i] * 64 + lane];
#pragma unroll
        for (int i = 0; i < 16; i += 4) {
            a0 += __uint_as_float(u[i] << 16);     a1 += __uint_as_float(u[i] & 0xFFFF0000u);
            b0 += __uint_as_float(u[i + 1] << 16); b1 += __uint_as_float(u[i + 1] & 0xFFFF0000u);
            c0 += __uint_as_float(u[i + 2] << 16); c1 += __uint_as_float(u[i + 2] & 0xFFFF0000u);
            d0 += __uint_as_float(u[i + 3] << 16); d1 += __uint_as_float(u[i + 3] & 0xFFFF0000u);
        }
    }
    for (; e + 4 <= end; e += 4) {
        int s0 = csr[e], s1 = csr[e + 1], s2 = csr[e + 2], s3 = csr[e + 3];
        unsigned u0 = hb[(size_t)s0 * 64 + lane];
        unsigned u1 = hb[(size_t)s1 * 64 + lane];
        unsigned u2 = hb[(size_t)s2 * 64 + lane];
        unsigned u3 = hb[(size_t)s3 * 64 + lane];
        a0 += __uint_as_float(u0 << 16); a1 += __uint_as_float(u0 & 0xFFFF0000u);
        b0 += __uint_as_float(u1 << 16); b1 += __uint_as_float(u1 & 0xFFFF0000u);
        c0 += __uint_as_float(u2 << 16); c1 += __uint_as_float(u2 & 0xFFFF0000u);
        d0 += __uint_as_float(u3 << 16); d1 += __uint_as_float(u3 & 0xFFFF0000u);
    }
    for (; e < end; ++e) {
        unsigned u = hb[(size_t)csr[e] * 64 + lane];
        a0 += __uint_as_float(u << 16);
        a1 += __uint_as_float(u & 0xFFFF0000u);
    }
    float iv = invd[n];
    unsigned o = f2bf((a0 + b0 + c0 + d0) * iv) | (f2bf((a1 + b1 + c1 + d1) * iv) << 16);
    aggb[(size_t)n * 64 + lane] = o;
}

// ---------------- MFMA fused: h_out = relu(agg@Wl + hin@Wr + b); pooled += per-graph sums ----
__global__ __launch_bounds__(256, 4) void k_gemm(
    const unsigned* __restrict__ aggb, const unsigned* __restrict__ hinb,
    const unsigned* __restrict__ wlh, const unsigned* __restrict__ wll,
    const unsigned* __restrict__ wrh, const unsigned* __restrict__ wrl,
    const float* __restrict__ bias, const int* __restrict__ batch,
    unsigned* __restrict__ houtb, float* __restrict__ pooled, int layer) {
    __shared__ float Ts[64 * 132];  // stride 132: epilogue writes <=2-way bank aliased
    __shared__ int bs[64];
    const int tx = threadIdx.x;
    const int wave = tx >> 6, lane = tx & 63;
    const int row0 = blockIdx.x * 64;
    const int lrow = lane & 15, kgrp = lane >> 4;

    if (tx < 64) {
        int grow = row0 + tx;
        bs[tx] = (grow < N_NODES) ? batch[grow] : -1;
    }

    f32x4 acc[4][2];
#pragma unroll
    for (int m = 0; m < 4; ++m)
#pragma unroll
        for (int n = 0; n < 2; ++n) acc[m][n] = (f32x4){0.f, 0.f, 0.f, 0.f};
    const short8 zf = {0, 0, 0, 0, 0, 0, 0, 0};

    for (int kc = 0; kc < 4; ++kc) {
        const int koff = kc * 16 + kgrp * 4;  // uint offset: k = kc*32 + kgrp*8 + (0..7)
        short8 af[4], hf[4];
#pragma unroll
        for (int m = 0; m < 4; ++m) {
            int r = row0 + m * 16 + lrow;
            if (r < N_NODES) {
                af[m] = *(const short8*)(aggb + (size_t)r * 64 + koff);
                hf[m] = *(const short8*)(hinb + (size_t)r * 64 + koff);
            } else {
                af[m] = zf;
                hf[m] = zf;
            }
        }
#pragma unroll
        for (int n = 0; n < 2; ++n) {
            int wn = wave * 2 + n;  // col tile 0..7
            size_t wbase = (size_t)(wn * 16 + lrow) * 64 + koff;
            short8 fl_h = *(const short8*)(wlh + wbase);
            short8 fl_l = *(const short8*)(wll + wbase);
            short8 fr_h = *(const short8*)(wrh + wbase);
            short8 fr_l = *(const short8*)(wrl + wbase);
#pragma unroll
            for (int m = 0; m < 4; ++m) {
                acc[m][n] = __builtin_amdgcn_mfma_f32_16x16x32_bf16(af[m], fl_h, acc[m][n], 0, 0, 0);
                acc[m][n] = __builtin_amdgcn_mfma_f32_16x16x32_bf16(af[m], fl_l, acc[m][n], 0, 0, 0);
                acc[m][n] = __builtin_amdgcn_mfma_f32_16x16x32_bf16(hf[m], fr_h, acc[m][n], 0, 0, 0);
                acc[m][n] = __builtin_amdgcn_mfma_f32_16x16x32_bf16(hf[m], fr_l, acc[m][n], 0, 0, 0);
            }
        }
    }

    // C/D layout: col = lane&15, row = (lane>>4)*4 + reg  [guide §3, m89-verified]
#pragma unroll
    for (int n = 0; n < 2; ++n) {
        int c = wave * 32 + n * 16 + lrow;
        float bb = bias[c];
#pragma unroll
        for (int m = 0; m < 4; ++m)
#pragma unroll
            for (int reg = 0; reg < 4; ++reg) {
                int r = m * 16 + kgrp * 4 + reg;
                Ts[r * 132 + c] = fmaxf(acc[m][n][reg] + bb, 0.f);
            }
    }
    __syncthreads();

    // bf16 h_out store, coalesced: 1024 uint4 tiles over [64][128]
#pragma unroll
    for (int it = 0; it < 4; ++it) {
        int f = it * 256 + tx;
        int r = f >> 4, slot = f & 15;
        int grow = row0 + r;
        if (grow < N_NODES) {
            const float* ts = &Ts[r * 132 + slot * 8];
            uint4 o;
            o.x = f2bf(ts[0]) | (f2bf(ts[1]) << 16);
            o.y = f2bf(ts[2]) | (f2bf(ts[3]) << 16);
            o.z = f2bf(ts[4]) | (f2bf(ts[5]) << 16);
            o.w = f2bf(ts[6]) | (f2bf(ts[7]) << 16);
            *(uint4*)(houtb + (size_t)grow * 64 + slot * 4) = o;
        }
    }

    // per-graph pooled pre-reduction: 256 threads = 128 cols x 2 row-halves (batch sorted)
    {
        int j = tx & 127, half = tx >> 7;
        int rbeg = half * 32, rend = rbeg + 32;
        float run = 0.f;
        int curb = bs[rbeg];
        for (int r = rbeg; r < rend; ++r) {
            int bb = bs[r];
            if (bb != curb) {
                if (curb >= 0)
                    atomicAdd(&pooled[(size_t)curb * (HID * N_LAYER) + layer * HID + j], run);
                run = 0.f;
                curb = bb;
            }
            run += Ts[r * 132 + j];
        }
        if (curb >= 0)
            atomicAdd(&pooled[(size_t)curb * (HID * N_LAYER) + layer * HID + j], run);
    }
}

// ---------------- FC head: one block per graph ----------------
__global__ void k_fc(const float* __restrict__ pooled, const float* __restrict__ counts,
                     const float* __restrict__ fc1w, const float* __restrict__ fc1b,
                     const float* __restrict__ fc2w, const float* __restrict__ fc2b,
                     float* __restrict__ out) {
    __shared__ float pr[HID * N_LAYER];
    __shared__ float a1[FC_HID];
    const int g = blockIdx.x, t = threadIdx.x;  // 256 threads
    float invc = 1.0f / fmaxf(counts[g], 1.0f);
    for (int i = t; i < HID * N_LAYER; i += FC_HID)
        pr[i] = pooled[(size_t)g * (HID * N_LAYER) + i] * invc;
    __syncthreads();
    float acc = fc1b[t];
    for (int k = 0; k < HID * N_LAYER; ++k)
        acc = fmaf(pr[k], fc1w[(size_t)k * FC_HID + t], acc);
    a1[t] = fmaxf(acc, 0.f);
    __syncthreads();
    if (t < N_CLASS) {
        float o = fc2b[t];
        for (int k = 0; k < FC_HID; ++k)
            o = fmaf(a1[k], fc2w[(size_t)k * N_CLASS + t], o);
        out[(size_t)g * N_CLASS + t] = o;
    }
}

extern "C" void kernel_launch(void* const* d_in, const int* in_sizes, int n_in,
                              void* d_out, int out_size, void* d_ws, size_t ws_size,
                              hipStream_t stream) {
    const float* x = (const float*)d_in[0];
    const int* ei = (const int*)d_in[1];
    const int* batch = (const int*)d_in[2];
    const float* Wl = (const float*)d_in[3];
    const float* Wr = (const float*)d_in[4];
    const float* bl = (const float*)d_in[5];
    const float* fc1w = (const float*)d_in[6];
    const float* fc1b = (const float*)d_in[7];
    const float* fc2w = (const float*)d_in[8];
    const float* fc2b = (const float*)d_in[9];
    float* out = (float*)d_out;

    char* ws = (char*)d_ws;
    size_t off = 0;
    auto alloc = [&](size_t bytes) {
        void* p = ws + off;
        off += (bytes + 255) & ~size_t(255);
        return p;
    };
    // all buffers fully written on-device every call -> no memsets needed
    int* emin = (int*)alloc(4);
    int* bmin = (int*)alloc(BIN_NB * 4);
    float* pooled = (float*)alloc((size_t)N_GRAPHS * HID * N_LAYER * 4);
    int* hist = (int*)alloc((size_t)BIN_NB * NBKT * 4);
    int* colex = (int*)alloc((size_t)BIN_NB * NBKT * 4);
    int* btot = (int*)alloc(NBKT * 4);
    int* bboff = (int*)alloc((NBKT + 1) * 4);
    int* rp = (int*)alloc((N_NODES + 1) * 4);
    float* invd = (float*)alloc(N_NODES * 4);
    float* counts = (float*)alloc(N_GRAPHS * 4);
    unsigned* ebuf = (unsigned*)alloc((size_t)N_EDGES * 4);
    int* csr = (int*)alloc((size_t)N_EDGES * 4);
    unsigned* wlh = (unsigned*)alloc((size_t)N_LAYER * HID * 64 * 4);
    unsigned* wll = (unsigned*)alloc((size_t)N_LAYER * HID * 64 * 4);
    unsigned* wrh = (unsigned*)alloc((size_t)N_LAYER * HID * 64 * 4);
    unsigned* wrl = (unsigned*)alloc((size_t)N_LAYER * HID * 64 * 4);
    unsigned* aggb = (unsigned*)alloc((size_t)N_NODES * 64 * 4);   // bf16x2 packed
    unsigned* xb = (unsigned*)alloc((size_t)N_NODES * 64 * 4);
    unsigned* hb1 = (unsigned*)alloc((size_t)N_NODES * 64 * 4);
    unsigned* hb2 = (unsigned*)alloc((size_t)N_NODES * 64 * 4);

    // ---- preprocessing: one cooperative kernel (fallback: discrete chain) ----
    {
        const int* ei_p = ei; const float* x_p = x;
        const float* Wl_p = Wl; const float* Wr_p = Wr;
        unsigned* xb_p = xb;
        unsigned* wlh_p = wlh; unsigned* wll_p = wll;
        unsigned* wrh_p = wrh; unsigned* wrl_p = wrl;
        float* pooled_p = pooled; int* bmin_p = bmin; int* hist_p = hist;
        int* colex_p = colex; int* btot_p = btot; int* bboff_p = bboff;
        int* rp_p = rp; int* emin_p = emin; const int* batch_p = batch;
        float* counts_p = counts; unsigned* ebuf_p = ebuf;
        float* invd_p = invd; int* csr_p = csr;
        void* args[] = {&ei_p, &x_p, &Wl_p, &Wr_p, &xb_p, &wlh_p, &wll_p, &wrh_p, &wrl_p,
                        &pooled_p, &bmin_p, &hist_p, &colex_p, &btot_p, &bboff_p,
                        &rp_p, &emin_p, &batch_p, &counts_p, &ebuf_p, &invd_p, &csr_p};
        hipError_t err = hipLaunchCooperativeKernel((const void*)k_prep_all, dim3(BIN_NB),
                                                    dim3(512), args, 0, stream);
        if (err != hipSuccess) {  // deterministic fallback: same math, discrete dispatches
            k_minh<<<BIN_NB, 512, 0, stream>>>(ei, bmin, hist);
            k_base<<<NBKT, BIN_NB, 0, stream>>>(hist, colex, btot, pooled);
            k_bscan<<<1, 128, 0, stream>>>(btot, bmin, bboff, rp, emin, batch, counts);
            k_bin<<<BIN_NB, 512, 0, stream>>>(ei, emin, bboff, colex, ebuf);
            k_scatter2<<<NBKT + 1, 512, 0, stream>>>(ebuf, bboff, emin, rp, invd, csr);
            k_cvtprep<<<6 + CVT_NB, 256, 0, stream>>>(x, xb, Wl, Wr, wlh, wll, wrh, wrl);
        }
    }

    const unsigned* hin = xb;
    unsigned* houts[3] = {hb1, hb2, hb1};
    for (int layer = 0; layer < N_LAYER; ++layer) {
        k_agg<<<N_NODES, 64, 0, stream>>>(hin, rp, csr, invd, aggb);
        k_gemm<<<(N_NODES + 63) / 64, 256, 0, stream>>>(
            aggb, hin,
            wlh + (size_t)layer * HID * 64, wll + (size_t)layer * HID * 64,
            wrh + (size_t)layer * HID * 64, wrl + (size_t)layer * HID * 64,
            bl + (size_t)layer * HID, batch, houts[layer], pooled, layer);
        hin = houts[layer];
    }
    k_fc<<<N_GRAPHS, 256, 0, stream>>>(pooled, counts, fc1w, fc1b, fc2w, fc2b, out);
}

// Round 14
// 249.432 us; speedup vs baseline: 2.1826x; 2.1826x over previous
//
#include <hip/hip_runtime.h>
#include <hip/hip_bf16.h>
#include <limits.h>

#define N_NODES 50000
#define N_EDGES 800000
#define HID 128
#define N_LAYER 3
#define FC_HID 256
#define N_CLASS 10
#define N_GRAPHS 64
#define NBKT 98                          // raw dst>>9; raw dst < 50000 -> buckets 0..97
#define BIN_NB 256                       // edge-slice blocks (k_minh / k_bin must match)
#define PER_BLK ((N_EDGES + BIN_NB - 1) / BIN_NB)  // 3125

typedef __attribute__((ext_vector_type(8))) short short8;   // 8 bf16 = 4 VGPRs
typedef __attribute__((ext_vector_type(4))) float f32x4;

__device__ inline unsigned f2bf(float f) {  // RNE f32 -> bf16 bits
    unsigned u = __float_as_uint(f);
    return (u + 0x7FFFu + ((u >> 16) & 1u)) >> 16;
}
__device__ inline float bf2f(unsigned b) { return __uint_as_float(b << 16); }

// ---- fused: edge min + bucket hist + x->bf16 cvt + W split-precision prep ----
// 256 blocks x 512 threads. cvt/wprep are independent payloads that overlap the edge scan.
__global__ __launch_bounds__(512) void k_minh(
    const int* __restrict__ ei, const float* __restrict__ x,
    const float* __restrict__ Wl, const float* __restrict__ Wr,
    int* __restrict__ bmin, int* __restrict__ hist, unsigned* __restrict__ xb,
    unsigned* __restrict__ wlh, unsigned* __restrict__ wll,
    unsigned* __restrict__ wrh, unsigned* __restrict__ wrl) {
    __shared__ int red[512];
    __shared__ int lh[NBKT];
    const int b = blockIdx.x, t = threadIdx.x;
    if (t < NBKT) lh[t] = 0;
    __syncthreads();
    int e0 = b * PER_BLK, e1 = min(e0 + PER_BLK, N_EDGES);
    int v = INT_MAX;
    for (int j = e0 + t; j < e1; j += 512) {
        int s = ei[j], d = ei[N_EDGES + j];
        v = min(v, min(s, d));
        atomicAdd(&lh[d >> 9], 1);
    }
    // x -> bf16x2 packed (grid-stride over 1.6M float4 groups)
    for (int i = b * 512 + t; i < N_NODES * HID / 4; i += BIN_NB * 512) {
        float4 xv = *(const float4*)(x + (size_t)i * 4);
        uint2 o;
        o.x = f2bf(xv.x) | (f2bf(xv.y) << 16);
        o.y = f2bf(xv.z) | (f2bf(xv.w) << 16);
        *(uint2*)(xb + (size_t)i * 2) = o;
    }
    if (b >= 250) {  // W prep: Wt[n][k], W ~= hi + lo; one matrix per block
        int w = b - 250;
        const float* src = (w < 3) ? (Wl + (size_t)w * HID * HID)
                                   : (Wr + (size_t)(w - 3) * HID * HID);
        unsigned* dh = (w < 3) ? (wlh + (size_t)w * HID * 64) : (wrh + (size_t)(w - 3) * HID * 64);
        unsigned* dl = (w < 3) ? (wll + (size_t)w * HID * 64) : (wrl + (size_t)(w - 3) * HID * 64);
        for (int i = 0; i < 16; ++i) {
            int u = t * 16 + i;           // n = u>>6 (out col), kk = u&63 (k pair)
            int n = u >> 6, kk = u & 63;
            float v0 = src[(size_t)(2 * kk) * HID + n];
            float v1 = src[(size_t)(2 * kk + 1) * HID + n];
            unsigned h0 = f2bf(v0), h1 = f2bf(v1);
            unsigned l0 = f2bf(v0 - bf2f(h0)), l1 = f2bf(v1 - bf2f(h1));
            dh[u] = h0 | (h1 << 16);
            dl[u] = l0 | (l1 << 16);
        }
    }
    red[t] = v;
    __syncthreads();
    for (int off = 256; off > 0; off >>= 1) {
        if (t < off) red[t] = min(red[t], red[t + off]);
        __syncthreads();
    }
    if (t == 0) bmin[b] = red[0];
    if (t < NBKT) hist[b * NBKT + t] = lh[t];
}

// ---- column scan over edge-slices -> colex, btot; + zero pooled; block0: emin + counts ----
__global__ void k_base(const int* __restrict__ hist, int* __restrict__ colex,
                       int* __restrict__ btot, float* __restrict__ pooled,
                       const int* __restrict__ bmin, int* __restrict__ emin,
                       const int* __restrict__ batch, float* __restrict__ counts) {
    __shared__ int s[BIN_NB];
    __shared__ int s2[BIN_NB];
    const int b = blockIdx.x, t = threadIdx.x;  // 98 blocks x 256 threads
    int gid = b * BIN_NB + t;                   // 25088 threads cover 24576 pooled elems
    if (gid < N_GRAPHS * HID * N_LAYER) pooled[gid] = 0.f;
    int v = hist[t * NBKT + b];
    s[t] = v;
    __syncthreads();
    for (int off = 1; off < BIN_NB; off <<= 1) {
        int u = (t >= off) ? s[t - off] : 0;
        __syncthreads();
        s[t] += u;
        __syncthreads();
    }
    colex[t * NBKT + b] = s[t] - v;
    if (t == BIN_NB - 1) btot[b] = s[t];
    if (b == 0) {  // extras: emin reduce over 256 block-mins; per-graph counts
        s2[t] = bmin[t];
        __syncthreads();
        for (int off = 128; off > 0; off >>= 1) {
            if (t < off) s2[t] = min(s2[t], s2[t + off]);
            __syncthreads();
        }
        if (t == 0) *emin = s2[0];
        if (t < N_GRAPHS) {
            int g = t;
            int lo = 0, hi = N_NODES;
            while (lo < hi) { int mid = (lo + hi) >> 1; if (batch[mid] < g) lo = mid + 1; else hi = mid; }
            int lb = lo;
            lo = lb; hi = N_NODES;
            while (lo < hi) { int mid = (lo + hi) >> 1; if (batch[mid] <= g) lo = mid + 1; else hi = mid; }
            counts[g] = (float)(lo - lb);
        }
    }
}

// ---- single-pass binning: edge -> bucket-contiguous packed ebuf (bboff scanned locally) ----
__global__ __launch_bounds__(512) void k_bin(const int* __restrict__ ei,
                                             const int* __restrict__ emin,
                                             const int* __restrict__ btot,
                                             const int* __restrict__ colex,
                                             unsigned* __restrict__ ebuf) {
    __shared__ int sb[128];
    __shared__ int lcnt[NBKT];
    __shared__ int lbase[NBKT];
    const int t = threadIdx.x, blk = blockIdx.x;
    int v = (t < NBKT) ? btot[t] : 0;
    if (t < 128) sb[t] = v;
    __syncthreads();
    for (int off = 1; off < 128; off <<= 1) {
        int u = (t >= off && t < 128) ? sb[t - off] : 0;
        __syncthreads();
        if (t < 128) sb[t] += u;
        __syncthreads();
    }
    if (t < NBKT) {
        lcnt[t] = 0;
        lbase[t] = (sb[t] - v) + colex[blk * NBKT + t];  // bboff[t] + colex
    }
    __syncthreads();
    int m = *emin;
    int e0 = blk * PER_BLK, e1 = min(e0 + PER_BLK, N_EDGES);
    for (int j = e0 + t; j < e1; j += 512) {
        int s = ei[j] - m, d = ei[N_EDGES + j];
        int bk = d >> 9;
        int idx = atomicAdd(&lcnt[bk], 1);
        ebuf[lbase[bk] + idx] = ((unsigned)s << 9) | (unsigned)(d & 511);
    }
}

// ---- per-bucket: local deg/scan -> rp, invd, then CSR placement (bboff scanned locally) ----
__global__ __launch_bounds__(512) void k_scatter2(const unsigned* __restrict__ ebuf,
                                                  const int* __restrict__ btot,
                                                  const int* __restrict__ emin,
                                                  int* __restrict__ rp,
                                                  float* __restrict__ invd,
                                                  int* __restrict__ csr) {
    __shared__ int ldeg[512];
    __shared__ int lsc[512];
    __shared__ int lfill[512];
    __shared__ int bbsh[NBKT + 1];
    const int b = blockIdx.x, t = threadIdx.x;
    // local exclusive scan of btot -> bbsh[0..98]
    int v = (t < NBKT) ? btot[t] : 0;
    if (t < 128) ldeg[t] = v;
    __syncthreads();
    for (int off = 1; off < 128; off <<= 1) {
        int u = (t >= off && t < 128) ? ldeg[t - off] : 0;
        __syncthreads();
        if (t < 128) ldeg[t] += u;
        __syncthreads();
    }
    if (t < NBKT) bbsh[t] = ldeg[t] - v;
    if (t == 127) bbsh[NBKT] = ldeg[127];
    __syncthreads();
    int m = *emin;
    if (b == NBKT) {  // tail: nodes past bucket coverage + rp[N_NODES]
        if (t == 0) rp[N_NODES] = bbsh[NBKT];
        for (int nd = NBKT * 512 - m + t; nd < N_NODES; nd += 512)
            if (nd >= 0) { rp[nd] = N_EDGES; invd[nd] = 1.0f; }
        return;
    }
    int beg = bbsh[b], end = bbsh[b + 1];
    ldeg[t] = 0;
    lfill[t] = 0;
    __syncthreads();
    for (int e = beg + t; e < end; e += 512)
        atomicAdd(&ldeg[ebuf[e] & 511], 1);
    __syncthreads();
    int dv = ldeg[t];
    lsc[t] = dv;
    __syncthreads();
    for (int off = 1; off < 512; off <<= 1) {
        int u = (t >= off) ? lsc[t - off] : 0;
        __syncthreads();
        lsc[t] += u;
        __syncthreads();
    }
    int base = beg + lsc[t] - dv;  // global CSR start for this node slot
    lsc[t] = base;
    int nd = (b << 9) + t - m;
    if (nd >= 0 && nd < N_NODES) {
        rp[nd] = base;
        invd[nd] = 1.0f / (float)max(dv, 1);
    }
    __syncthreads();
    for (int e = beg + t; e < end; e += 512) {
        unsigned p = ebuf[e];
        int loc = p & 511;
        int pos = lsc[loc] + atomicAdd(&lfill[loc], 1);
        csr[pos] = (int)(p >> 9);
    }
}

// ---------------- mean aggregation: one wave per node, full 256B rows, 16-deep MLP ----------
__global__ void k_agg(const unsigned* __restrict__ hb, const int* __restrict__ rp,
                      const int* __restrict__ csr, const float* __restrict__ invd,
                      unsigned* __restrict__ aggb) {
    const int n = blockIdx.x;
    const int lane = threadIdx.x;  // 64; lane covers features 2*lane, 2*lane+1
    int beg = rp[n], end = rp[n + 1];
    float a0 = 0, a1 = 0, b0 = 0, b1 = 0, c0 = 0, c1 = 0, d0 = 0, d1 = 0;
    int e = beg;
    for (; e + 16 <= end; e += 16) {  // 16 outstanding loads: one batch covers avg degree
        int s[16];
        unsigned u[16];
#pragma unroll
        for (int i = 0; i < 16; ++i) s[i] = csr[e + i];
#pragma unroll
        for (int i = 0; i < 16; ++i) u[i] = hb[(size_t)s[i] * 64 + lane];
#pragma unroll
        for (int i = 0; i < 16; i += 4) {
            a0 += __uint_as_float(u[i] << 16);     a1 += __uint_as_float(u[i] & 0xFFFF0000u);
            b0 += __uint_as_float(u[i + 1] << 16); b1 += __uint_as_float(u[i + 1] & 0xFFFF0000u);
            c0 += __uint_as_float(u[i + 2] << 16); c1 += __uint_as_float(u[i + 2] & 0xFFFF0000u);
            d0 += __uint_as_float(u[i + 3] << 16); d1 += __uint_as_float(u[i + 3] & 0xFFFF0000u);
        }
    }
    for (; e + 4 <= end; e += 4) {
        int s0 = csr[e], s1 = csr[e + 1], s2 = csr[e + 2], s3 = csr[e + 3];
        unsigned u0 = hb[(size_t)s0 * 64 + lane];
        unsigned u1 = hb[(size_t)s1 * 64 + lane];
        unsigned u2 = hb[(size_t)s2 * 64 + lane];
        unsigned u3 = hb[(size_t)s3 * 64 + lane];
        a0 += __uint_as_float(u0 << 16); a1 += __uint_as_float(u0 & 0xFFFF0000u);
        b0 += __uint_as_float(u1 << 16); b1 += __uint_as_float(u1 & 0xFFFF0000u);
        c0 += __uint_as_float(u2 << 16); c1 += __uint_as_float(u2 & 0xFFFF0000u);
        d0 += __uint_as_float(u3 << 16); d1 += __uint_as_float(u3 & 0xFFFF0000u);
    }
    for (; e < end; ++e) {
        unsigned u = hb[(size_t)csr[e] * 64 + lane];
        a0 += __uint_as_float(u << 16);
        a1 += __uint_as_float(u & 0xFFFF0000u);
    }
    float iv = invd[n];
    unsigned o = f2bf((a0 + b0 + c0 + d0) * iv) | (f2bf((a1 + b1 + c1 + d1) * iv) << 16);
    aggb[(size_t)n * 64 + lane] = o;
}

// ---------------- MFMA fused: h_out = relu(agg@Wl + hin@Wr + b); pooled += per-graph sums ----
__global__ __launch_bounds__(256, 4) void k_gemm(
    const unsigned* __restrict__ aggb, const unsigned* __restrict__ hinb,
    const unsigned* __restrict__ wlh, const unsigned* __restrict__ wll,
    const unsigned* __restrict__ wrh, const unsigned* __restrict__ wrl,
    const float* __restrict__ bias, const int* __restrict__ batch,
    unsigned* __restrict__ houtb, float* __restrict__ pooled, int layer, int store_h) {
    __shared__ float Ts[64 * 132];  // stride 132: epilogue writes <=2-way bank aliased
    __shared__ int bs[64];
    const int tx = threadIdx.x;
    const int wave = tx >> 6, lane = tx & 63;
    const int row0 = blockIdx.x * 64;
    const int lrow = lane & 15, kgrp = lane >> 4;

    if (tx < 64) {
        int grow = row0 + tx;
        bs[tx] = (grow < N_NODES) ? batch[grow] : -1;
    }

    f32x4 acc[4][2];
#pragma unroll
    for (int m = 0; m < 4; ++m)
#pragma unroll
        for (int n = 0; n < 2; ++n) acc[m][n] = (f32x4){0.f, 0.f, 0.f, 0.f};
    const short8 zf = {0, 0, 0, 0, 0, 0, 0, 0};

    for (int kc = 0; kc < 4; ++kc) {
        const int koff = kc * 16 + kgrp * 4;  // uint offset: k = kc*32 + kgrp*8 + (0..7)
        short8 af[4], hf[4];
#pragma unroll
        for (int m = 0; m < 4; ++m) {
            int r = row0 + m * 16 + lrow;
            if (r < N_NODES) {
                af[m] = *(const short8*)(aggb + (size_t)r * 64 + koff);
                hf[m] = *(const short8*)(hinb + (size_t)r * 64 + koff);
            } else {
                af[m] = zf;
                hf[m] = zf;
            }
        }
#pragma unroll
        for (int n = 0; n < 2; ++n) {
            int wn = wave * 2 + n;  // col tile 0..7
            size_t wbase = (size_t)(wn * 16 + lrow) * 64 + koff;
            short8 fl_h = *(const short8*)(wlh + wbase);
            short8 fl_l = *(const short8*)(wll + wbase);
            short8 fr_h = *(const short8*)(wrh + wbase);
            short8 fr_l = *(const short8*)(wrl + wbase);
#pragma unroll
            for (int m = 0; m < 4; ++m) {
                acc[m][n] = __builtin_amdgcn_mfma_f32_16x16x32_bf16(af[m], fl_h, acc[m][n], 0, 0, 0);
                acc[m][n] = __builtin_amdgcn_mfma_f32_16x16x32_bf16(af[m], fl_l, acc[m][n], 0, 0, 0);
                acc[m][n] = __builtin_amdgcn_mfma_f32_16x16x32_bf16(hf[m], fr_h, acc[m][n], 0, 0, 0);
                acc[m][n] = __builtin_amdgcn_mfma_f32_16x16x32_bf16(hf[m], fr_l, acc[m][n], 0, 0, 0);
            }
        }
    }

    // C/D layout: col = lane&15, row = (lane>>4)*4 + reg  [guide §3, m89-verified]
#pragma unroll
    for (int n = 0; n < 2; ++n) {
        int c = wave * 32 + n * 16 + lrow;
        float bb = bias[c];
#pragma unroll
        for (int m = 0; m < 4; ++m)
#pragma unroll
            for (int reg = 0; reg < 4; ++reg) {
                int r = m * 16 + kgrp * 4 + reg;
                Ts[r * 132 + c] = fmaxf(acc[m][n][reg] + bb, 0.f);
            }
    }
    __syncthreads();

    // bf16 h_out store (skipped for the last layer - no consumer)
    if (store_h) {
#pragma unroll
        for (int it = 0; it < 4; ++it) {
            int f = it * 256 + tx;
            int r = f >> 4, slot = f & 15;
            int grow = row0 + r;
            if (grow < N_NODES) {
                const float* ts = &Ts[r * 132 + slot * 8];
                uint4 o;
                o.x = f2bf(ts[0]) | (f2bf(ts[1]) << 16);
                o.y = f2bf(ts[2]) | (f2bf(ts[3]) << 16);
                o.z = f2bf(ts[4]) | (f2bf(ts[5]) << 16);
                o.w = f2bf(ts[6]) | (f2bf(ts[7]) << 16);
                *(uint4*)(houtb + (size_t)grow * 64 + slot * 4) = o;
            }
        }
    }

    // per-graph pooled pre-reduction: 256 threads = 128 cols x 2 row-halves (batch sorted)
    {
        int j = tx & 127, half = tx >> 7;
        int rbeg = half * 32, rend = rbeg + 32;
        float run = 0.f;
        int curb = bs[rbeg];
        for (int r = rbeg; r < rend; ++r) {
            int bb = bs[r];
            if (bb != curb) {
                if (curb >= 0)
                    atomicAdd(&pooled[(size_t)curb * (HID * N_LAYER) + layer * HID + j], run);
                run = 0.f;
                curb = bb;
            }
            run += Ts[r * 132 + j];
        }
        if (curb >= 0)
            atomicAdd(&pooled[(size_t)curb * (HID * N_LAYER) + layer * HID + j], run);
    }
}

// ---------------- FC head: one block per graph ----------------
__global__ void k_fc(const float* __restrict__ pooled, const float* __restrict__ counts,
                     const float* __restrict__ fc1w, const float* __restrict__ fc1b,
                     const float* __restrict__ fc2w, const float* __restrict__ fc2b,
                     float* __restrict__ out) {
    __shared__ float pr[HID * N_LAYER];
    __shared__ float a1[FC_HID];
    const int g = blockIdx.x, t = threadIdx.x;  // 256 threads
    float invc = 1.0f / fmaxf(counts[g], 1.0f);
    for (int i = t; i < HID * N_LAYER; i += FC_HID)
        pr[i] = pooled[(size_t)g * (HID * N_LAYER) + i] * invc;
    __syncthreads();
    float acc = fc1b[t];
    for (int k = 0; k < HID * N_LAYER; ++k)
        acc = fmaf(pr[k], fc1w[(size_t)k * FC_HID + t], acc);
    a1[t] = fmaxf(acc, 0.f);
    __syncthreads();
    if (t < N_CLASS) {
        float o = fc2b[t];
        for (int k = 0; k < FC_HID; ++k)
            o = fmaf(a1[k], fc2w[(size_t)k * N_CLASS + t], o);
        out[(size_t)g * N_CLASS + t] = o;
    }
}

extern "C" void kernel_launch(void* const* d_in, const int* in_sizes, int n_in,
                              void* d_out, int out_size, void* d_ws, size_t ws_size,
                              hipStream_t stream) {
    const float* x = (const float*)d_in[0];
    const int* ei = (const int*)d_in[1];
    const int* batch = (const int*)d_in[2];
    const float* Wl = (const float*)d_in[3];
    const float* Wr = (const float*)d_in[4];
    const float* bl = (const float*)d_in[5];
    const float* fc1w = (const float*)d_in[6];
    const float* fc1b = (const float*)d_in[7];
    const float* fc2w = (const float*)d_in[8];
    const float* fc2b = (const float*)d_in[9];
    float* out = (float*)d_out;

    char* ws = (char*)d_ws;
    size_t off = 0;
    auto alloc = [&](size_t bytes) {
        void* p = ws + off;
        off += (bytes + 255) & ~size_t(255);
        return p;
    };
    // all buffers fully written on-device every call -> no memsets needed
    int* emin = (int*)alloc(4);
    int* bmin = (int*)alloc(BIN_NB * 4);
    float* pooled = (float*)alloc((size_t)N_GRAPHS * HID * N_LAYER * 4);  // zeroed by k_base
    int* hist = (int*)alloc((size_t)BIN_NB * NBKT * 4);
    int* colex = (int*)alloc((size_t)BIN_NB * NBKT * 4);
    int* btot = (int*)alloc(NBKT * 4);
    int* rp = (int*)alloc((N_NODES + 1) * 4);
    float* invd = (float*)alloc(N_NODES * 4);
    float* counts = (float*)alloc(N_GRAPHS * 4);
    unsigned* ebuf = (unsigned*)alloc((size_t)N_EDGES * 4);
    int* csr = (int*)alloc((size_t)N_EDGES * 4);
    unsigned* wlh = (unsigned*)alloc((size_t)N_LAYER * HID * 64 * 4);
    unsigned* wll = (unsigned*)alloc((size_t)N_LAYER * HID * 64 * 4);
    unsigned* wrh = (unsigned*)alloc((size_t)N_LAYER * HID * 64 * 4);
    unsigned* wrl = (unsigned*)alloc((size_t)N_LAYER * HID * 64 * 4);
    unsigned* aggb = (unsigned*)alloc((size_t)N_NODES * 64 * 4);   // bf16x2 packed
    unsigned* xb = (unsigned*)alloc((size_t)N_NODES * 64 * 4);
    unsigned* hb1 = (unsigned*)alloc((size_t)N_NODES * 64 * 4);
    unsigned* hb2 = (unsigned*)alloc((size_t)N_NODES * 64 * 4);

    k_minh<<<BIN_NB, 512, 0, stream>>>(ei, x, Wl, Wr, bmin, hist, xb, wlh, wll, wrh, wrl);
    k_base<<<NBKT, BIN_NB, 0, stream>>>(hist, colex, btot, pooled, bmin, emin, batch, counts);
    k_bin<<<BIN_NB, 512, 0, stream>>>(ei, emin, btot, colex, ebuf);
    k_scatter2<<<NBKT + 1, 512, 0, stream>>>(ebuf, btot, emin, rp, invd, csr);

    const unsigned* hin = xb;
    unsigned* houts[3] = {hb1, hb2, hb1};
    for (int layer = 0; layer < N_LAYER; ++layer) {
        k_agg<<<N_NODES, 64, 0, stream>>>(hin, rp, csr, invd, aggb);
        k_gemm<<<(N_NODES + 63) / 64, 256, 0, stream>>>(
            aggb, hin,
            wlh + (size_t)layer * HID * 64, wll + (size_t)layer * HID * 64,
            wrh + (size_t)layer * HID * 64, wrl + (size_t)layer * HID * 64,
            bl + (size_t)layer * HID, batch, houts[layer], pooled, layer,
            layer < N_LAYER - 1 ? 1 : 0);
        hin = houts[layer];
    }
    k_fc<<<N_GRAPHS, 256, 0, stream>>>(pooled, counts, fc1w, fc1b, fc2w, fc2b, out);
}

// Round 15
// 224.961 us; speedup vs baseline: 2.4201x; 1.1088x over previous
//
#include <hip/hip_runtime.h>
#include <hip/hip_bf16.h>
#include <limits.h>

#define N_NODES 50000
#define N_EDGES 800000
#define HID 128
#define N_LAYER 3
#define FC_HID 256
#define N_CLASS 10
#define N_GRAPHS 64
#define NBKT 98                          // raw dst>>9; raw dst < 50000 -> buckets 0..97
#define BIN_NB 256                       // edge-slice blocks (k_minh / k_bin must match)
#define PER_BLK ((N_EDGES + BIN_NB - 1) / BIN_NB)  // 3125

typedef __attribute__((ext_vector_type(8))) short short8;   // 8 bf16 = 4 VGPRs
typedef __attribute__((ext_vector_type(4))) float f32x4;

__device__ inline unsigned f2bf(float f) {  // RNE f32 -> bf16 bits
    unsigned u = __float_as_uint(f);
    return (u + 0x7FFFu + ((u >> 16) & 1u)) >> 16;
}

// ---- fused: edge min + bucket hist + x->bf16 cvt + W bf16 transpose prep ----
// 256 blocks x 512 threads. cvt/wprep are independent payloads that overlap the edge scan.
__global__ __launch_bounds__(512) void k_minh(
    const int* __restrict__ ei, const float* __restrict__ x,
    const float* __restrict__ Wl, const float* __restrict__ Wr,
    int* __restrict__ bmin, int* __restrict__ hist, unsigned* __restrict__ xb,
    unsigned* __restrict__ wlh, unsigned* __restrict__ wrh) {
    __shared__ int red[512];
    __shared__ int lh[NBKT];
    const int b = blockIdx.x, t = threadIdx.x;
    if (t < NBKT) lh[t] = 0;
    __syncthreads();
    int e0 = b * PER_BLK, e1 = min(e0 + PER_BLK, N_EDGES);
    int v = INT_MAX;
    for (int j = e0 + t; j < e1; j += 512) {
        int s = ei[j], d = ei[N_EDGES + j];
        v = min(v, min(s, d));
        atomicAdd(&lh[d >> 9], 1);
    }
    // x -> bf16x2 packed (grid-stride over 1.6M float4 groups)
    for (int i = b * 512 + t; i < N_NODES * HID / 4; i += BIN_NB * 512) {
        float4 xv = *(const float4*)(x + (size_t)i * 4);
        uint2 o;
        o.x = f2bf(xv.x) | (f2bf(xv.y) << 16);
        o.y = f2bf(xv.z) | (f2bf(xv.w) << 16);
        *(uint2*)(xb + (size_t)i * 2) = o;
    }
    if (b >= 250) {  // W prep: Wt[n][k] bf16; one matrix per block
        int w = b - 250;
        const float* src = (w < 3) ? (Wl + (size_t)w * HID * HID)
                                   : (Wr + (size_t)(w - 3) * HID * HID);
        unsigned* dh = (w < 3) ? (wlh + (size_t)w * HID * 64) : (wrh + (size_t)(w - 3) * HID * 64);
        for (int i = 0; i < 16; ++i) {
            int u = t * 16 + i;           // n = u>>6 (out col), kk = u&63 (k pair)
            int n = u >> 6, kk = u & 63;
            float v0 = src[(size_t)(2 * kk) * HID + n];
            float v1 = src[(size_t)(2 * kk + 1) * HID + n];
            dh[u] = f2bf(v0) | (f2bf(v1) << 16);
        }
    }
    red[t] = v;
    __syncthreads();
    for (int off = 256; off > 0; off >>= 1) {
        if (t < off) red[t] = min(red[t], red[t + off]);
        __syncthreads();
    }
    if (t == 0) bmin[b] = red[0];
    if (t < NBKT) hist[b * NBKT + t] = lh[t];
}

// ---- column scan over edge-slices -> colex, btot; + zero pooled; block0: emin + counts ----
__global__ void k_base(const int* __restrict__ hist, int* __restrict__ colex,
                       int* __restrict__ btot, float* __restrict__ pooled,
                       const int* __restrict__ bmin, int* __restrict__ emin,
                       const int* __restrict__ batch, float* __restrict__ counts) {
    __shared__ int s[BIN_NB];
    __shared__ int s2[BIN_NB];
    const int b = blockIdx.x, t = threadIdx.x;  // 98 blocks x 256 threads
    int gid = b * BIN_NB + t;                   // 25088 threads cover 24576 pooled elems
    if (gid < N_GRAPHS * HID * N_LAYER) pooled[gid] = 0.f;
    int v = hist[t * NBKT + b];
    s[t] = v;
    __syncthreads();
    for (int off = 1; off < BIN_NB; off <<= 1) {
        int u = (t >= off) ? s[t - off] : 0;
        __syncthreads();
        s[t] += u;
        __syncthreads();
    }
    colex[t * NBKT + b] = s[t] - v;
    if (t == BIN_NB - 1) btot[b] = s[t];
    if (b == 0) {  // extras: emin reduce over 256 block-mins; per-graph counts
        s2[t] = bmin[t];
        __syncthreads();
        for (int off = 128; off > 0; off >>= 1) {
            if (t < off) s2[t] = min(s2[t], s2[t + off]);
            __syncthreads();
        }
        if (t == 0) *emin = s2[0];
        if (t < N_GRAPHS) {
            int g = t;
            int lo = 0, hi = N_NODES;
            while (lo < hi) { int mid = (lo + hi) >> 1; if (batch[mid] < g) lo = mid + 1; else hi = mid; }
            int lb = lo;
            lo = lb; hi = N_NODES;
            while (lo < hi) { int mid = (lo + hi) >> 1; if (batch[mid] <= g) lo = mid + 1; else hi = mid; }
            counts[g] = (float)(lo - lb);
        }
    }
}

// ---- single-pass binning: edge -> bucket-contiguous packed ebuf (bboff scanned locally) ----
__global__ __launch_bounds__(512) void k_bin(const int* __restrict__ ei,
                                             const int* __restrict__ emin,
                                             const int* __restrict__ btot,
                                             const int* __restrict__ colex,
                                             unsigned* __restrict__ ebuf) {
    __shared__ int sb[128];
    __shared__ int lcnt[NBKT];
    __shared__ int lbase[NBKT];
    const int t = threadIdx.x, blk = blockIdx.x;
    int v = (t < NBKT) ? btot[t] : 0;
    if (t < 128) sb[t] = v;
    __syncthreads();
    for (int off = 1; off < 128; off <<= 1) {
        int u = (t >= off && t < 128) ? sb[t - off] : 0;
        __syncthreads();
        if (t < 128) sb[t] += u;
        __syncthreads();
    }
    if (t < NBKT) {
        lcnt[t] = 0;
        lbase[t] = (sb[t] - v) + colex[blk * NBKT + t];  // bboff[t] + colex
    }
    __syncthreads();
    int m = *emin;
    int e0 = blk * PER_BLK, e1 = min(e0 + PER_BLK, N_EDGES);
    for (int j = e0 + t; j < e1; j += 512) {
        int s = ei[j] - m, d = ei[N_EDGES + j];
        int bk = d >> 9;
        int idx = atomicAdd(&lcnt[bk], 1);
        ebuf[lbase[bk] + idx] = ((unsigned)s << 9) | (unsigned)(d & 511);
    }
}

// ---- per-bucket: local deg/scan -> rp, invd, then CSR placement (bboff scanned locally) ----
__global__ __launch_bounds__(512) void k_scatter2(const unsigned* __restrict__ ebuf,
                                                  const int* __restrict__ btot,
                                                  const int* __restrict__ emin,
                                                  int* __restrict__ rp,
                                                  float* __restrict__ invd,
                                                  int* __restrict__ csr) {
    __shared__ int ldeg[512];
    __shared__ int lsc[512];
    __shared__ int lfill[512];
    __shared__ int bbsh[NBKT + 1];
    const int b = blockIdx.x, t = threadIdx.x;
    // local exclusive scan of btot -> bbsh[0..98]
    int v = (t < NBKT) ? btot[t] : 0;
    if (t < 128) ldeg[t] = v;
    __syncthreads();
    for (int off = 1; off < 128; off <<= 1) {
        int u = (t >= off && t < 128) ? ldeg[t - off] : 0;
        __syncthreads();
        if (t < 128) ldeg[t] += u;
        __syncthreads();
    }
    if (t < NBKT) bbsh[t] = ldeg[t] - v;
    if (t == 127) bbsh[NBKT] = ldeg[127];
    __syncthreads();
    int m = *emin;
    if (b == NBKT) {  // tail: nodes past bucket coverage + rp[N_NODES]
        if (t == 0) rp[N_NODES] = bbsh[NBKT];
        for (int nd = NBKT * 512 - m + t; nd < N_NODES; nd += 512)
            if (nd >= 0) { rp[nd] = N_EDGES; invd[nd] = 1.0f; }
        return;
    }
    int beg = bbsh[b], end = bbsh[b + 1];
    ldeg[t] = 0;
    lfill[t] = 0;
    __syncthreads();
    for (int e = beg + t; e < end; e += 512)
        atomicAdd(&ldeg[ebuf[e] & 511], 1);
    __syncthreads();
    int dv = ldeg[t];
    lsc[t] = dv;
    __syncthreads();
    for (int off = 1; off < 512; off <<= 1) {
        int u = (t >= off) ? lsc[t - off] : 0;
        __syncthreads();
        lsc[t] += u;
        __syncthreads();
    }
    int base = beg + lsc[t] - dv;  // global CSR start for this node slot
    lsc[t] = base;
    int nd = (b << 9) + t - m;
    if (nd >= 0 && nd < N_NODES) {
        rp[nd] = base;
        invd[nd] = 1.0f / (float)max(dv, 1);
    }
    __syncthreads();
    for (int e = beg + t; e < end; e += 512) {
        unsigned p = ebuf[e];
        int loc = p & 511;
        int pos = lsc[loc] + atomicAdd(&lfill[loc], 1);
        csr[pos] = (int)(p >> 9);
    }
}

// ---------------- mean aggregation: one wave per node, full 256B rows, 16-deep MLP ----------
__global__ void k_agg(const unsigned* __restrict__ hb, const int* __restrict__ rp,
                      const int* __restrict__ csr, const float* __restrict__ invd,
                      unsigned* __restrict__ aggb) {
    const int n = blockIdx.x;
    const int lane = threadIdx.x;  // 64; lane covers features 2*lane, 2*lane+1
    int beg = rp[n], end = rp[n + 1];
    float a0 = 0, a1 = 0, b0 = 0, b1 = 0, c0 = 0, c1 = 0, d0 = 0, d1 = 0;
    int e = beg;
    for (; e + 16 <= end; e += 16) {  // 16 outstanding loads: one batch covers avg degree
        int s[16];
        unsigned u[16];
#pragma unroll
        for (int i = 0; i < 16; ++i) s[i] = csr[e + i];
#pragma unroll
        for (int i = 0; i < 16; ++i) u[i] = hb[(size_t)s[i] * 64 + lane];
#pragma unroll
        for (int i = 0; i < 16; i += 4) {
            a0 += __uint_as_float(u[i] << 16);     a1 += __uint_as_float(u[i] & 0xFFFF0000u);
            b0 += __uint_as_float(u[i + 1] << 16); b1 += __uint_as_float(u[i + 1] & 0xFFFF0000u);
            c0 += __uint_as_float(u[i + 2] << 16); c1 += __uint_as_float(u[i + 2] & 0xFFFF0000u);
            d0 += __uint_as_float(u[i + 3] << 16); d1 += __uint_as_float(u[i + 3] & 0xFFFF0000u);
        }
    }
    for (; e + 4 <= end; e += 4) {
        int s0 = csr[e], s1 = csr[e + 1], s2 = csr[e + 2], s3 = csr[e + 3];
        unsigned u0 = hb[(size_t)s0 * 64 + lane];
        unsigned u1 = hb[(size_t)s1 * 64 + lane];
        unsigned u2 = hb[(size_t)s2 * 64 + lane];
        unsigned u3 = hb[(size_t)s3 * 64 + lane];
        a0 += __uint_as_float(u0 << 16); a1 += __uint_as_float(u0 & 0xFFFF0000u);
        b0 += __uint_as_float(u1 << 16); b1 += __uint_as_float(u1 & 0xFFFF0000u);
        c0 += __uint_as_float(u2 << 16); c1 += __uint_as_float(u2 & 0xFFFF0000u);
        d0 += __uint_as_float(u3 << 16); d1 += __uint_as_float(u3 & 0xFFFF0000u);
    }
    for (; e < end; ++e) {
        unsigned u = hb[(size_t)csr[e] * 64 + lane];
        a0 += __uint_as_float(u << 16);
        a1 += __uint_as_float(u & 0xFFFF0000u);
    }
    float iv = invd[n];
    unsigned o = f2bf((a0 + b0 + c0 + d0) * iv) | (f2bf((a1 + b1 + c1 + d1) * iv) << 16);
    aggb[(size_t)n * 64 + lane] = o;
}

// ---------------- MFMA fused: h_out = relu(agg@Wl + hin@Wr + b); pooled += per-graph sums ----
__global__ __launch_bounds__(256, 4) void k_gemm(
    const unsigned* __restrict__ aggb, const unsigned* __restrict__ hinb,
    const unsigned* __restrict__ wlh, const unsigned* __restrict__ wrh,
    const float* __restrict__ bias, const int* __restrict__ batch,
    unsigned* __restrict__ houtb, float* __restrict__ pooled, int layer, int store_h) {
    __shared__ float Ts[64 * 132];  // stride 132: epilogue writes <=2-way bank aliased
    __shared__ int bs[64];
    const int tx = threadIdx.x;
    const int wave = tx >> 6, lane = tx & 63;
    const int row0 = blockIdx.x * 64;
    const int lrow = lane & 15, kgrp = lane >> 4;

    if (tx < 64) {
        int grow = row0 + tx;
        bs[tx] = (grow < N_NODES) ? batch[grow] : -1;
    }

    f32x4 acc[4][2];
#pragma unroll
    for (int m = 0; m < 4; ++m)
#pragma unroll
        for (int n = 0; n < 2; ++n) acc[m][n] = (f32x4){0.f, 0.f, 0.f, 0.f};
    const short8 zf = {0, 0, 0, 0, 0, 0, 0, 0};

    for (int kc = 0; kc < 4; ++kc) {
        const int koff = kc * 16 + kgrp * 4;  // uint offset: k = kc*32 + kgrp*8 + (0..7)
        short8 af[4], hf[4];
#pragma unroll
        for (int m = 0; m < 4; ++m) {
            int r = row0 + m * 16 + lrow;
            if (r < N_NODES) {
                af[m] = *(const short8*)(aggb + (size_t)r * 64 + koff);
                hf[m] = *(const short8*)(hinb + (size_t)r * 64 + koff);
            } else {
                af[m] = zf;
                hf[m] = zf;
            }
        }
#pragma unroll
        for (int n = 0; n < 2; ++n) {
            int wn = wave * 2 + n;  // col tile 0..7
            size_t wbase = (size_t)(wn * 16 + lrow) * 64 + koff;
            short8 fl = *(const short8*)(wlh + wbase);
            short8 fr = *(const short8*)(wrh + wbase);
#pragma unroll
            for (int m = 0; m < 4; ++m) {
                acc[m][n] = __builtin_amdgcn_mfma_f32_16x16x32_bf16(af[m], fl, acc[m][n], 0, 0, 0);
                acc[m][n] = __builtin_amdgcn_mfma_f32_16x16x32_bf16(hf[m], fr, acc[m][n], 0, 0, 0);
            }
        }
    }

    // C/D layout: col = lane&15, row = (lane>>4)*4 + reg  [guide §3, m89-verified]
#pragma unroll
    for (int n = 0; n < 2; ++n) {
        int c = wave * 32 + n * 16 + lrow;
        float bb = bias[c];
#pragma unroll
        for (int m = 0; m < 4; ++m)
#pragma unroll
            for (int reg = 0; reg < 4; ++reg) {
                int r = m * 16 + kgrp * 4 + reg;
                Ts[r * 132 + c] = fmaxf(acc[m][n][reg] + bb, 0.f);
            }
    }
    __syncthreads();

    // bf16 h_out store (skipped for the last layer - no consumer)
    if (store_h) {
#pragma unroll
        for (int it = 0; it < 4; ++it) {
            int f = it * 256 + tx;
            int r = f >> 4, slot = f & 15;
            int grow = row0 + r;
            if (grow < N_NODES) {
                const float* ts = &Ts[r * 132 + slot * 8];
                uint4 o;
                o.x = f2bf(ts[0]) | (f2bf(ts[1]) << 16);
                o.y = f2bf(ts[2]) | (f2bf(ts[3]) << 16);
                o.z = f2bf(ts[4]) | (f2bf(ts[5]) << 16);
                o.w = f2bf(ts[6]) | (f2bf(ts[7]) << 16);
                *(uint4*)(houtb + (size_t)grow * 64 + slot * 4) = o;
            }
        }
    }

    // per-graph pooled pre-reduction: 256 threads = 128 cols x 2 row-halves (batch sorted)
    {
        int j = tx & 127, half = tx >> 7;
        int rbeg = half * 32, rend = rbeg + 32;
        float run = 0.f;
        int curb = bs[rbeg];
        for (int r = rbeg; r < rend; ++r) {
            int bb = bs[r];
            if (bb != curb) {
                if (curb >= 0)
                    atomicAdd(&pooled[(size_t)curb * (HID * N_LAYER) + layer * HID + j], run);
                run = 0.f;
                curb = bb;
            }
            run += Ts[r * 132 + j];
        }
        if (curb >= 0)
            atomicAdd(&pooled[(size_t)curb * (HID * N_LAYER) + layer * HID + j], run);
    }
}

// ---------------- FC head: one block per graph ----------------
__global__ void k_fc(const float* __restrict__ pooled, const float* __restrict__ counts,
                     const float* __restrict__ fc1w, const float* __restrict__ fc1b,
                     const float* __restrict__ fc2w, const float* __restrict__ fc2b,
                     float* __restrict__ out) {
    __shared__ float pr[HID * N_LAYER];
    __shared__ float a1[FC_HID];
    const int g = blockIdx.x, t = threadIdx.x;  // 256 threads
    float invc = 1.0f / fmaxf(counts[g], 1.0f);
    for (int i = t; i < HID * N_LAYER; i += FC_HID)
        pr[i] = pooled[(size_t)g * (HID * N_LAYER) + i] * invc;
    __syncthreads();
    float acc = fc1b[t];
    for (int k = 0; k < HID * N_LAYER; ++k)
        acc = fmaf(pr[k], fc1w[(size_t)k * FC_HID + t], acc);
    a1[t] = fmaxf(acc, 0.f);
    __syncthreads();
    if (t < N_CLASS) {
        float o = fc2b[t];
        for (int k = 0; k < FC_HID; ++k)
            o = fmaf(a1[k], fc2w[(size_t)k * N_CLASS + t], o);
        out[(size_t)g * N_CLASS + t] = o;
    }
}

extern "C" void kernel_launch(void* const* d_in, const int* in_sizes, int n_in,
                              void* d_out, int out_size, void* d_ws, size_t ws_size,
                              hipStream_t stream) {
    const float* x = (const float*)d_in[0];
    const int* ei = (const int*)d_in[1];
    const int* batch = (const int*)d_in[2];
    const float* Wl = (const float*)d_in[3];
    const float* Wr = (const float*)d_in[4];
    const float* bl = (const float*)d_in[5];
    const float* fc1w = (const float*)d_in[6];
    const float* fc1b = (const float*)d_in[7];
    const float* fc2w = (const float*)d_in[8];
    const float* fc2b = (const float*)d_in[9];
    float* out = (float*)d_out;

    char* ws = (char*)d_ws;
    size_t off = 0;
    auto alloc = [&](size_t bytes) {
        void* p = ws + off;
        off += (bytes + 255) & ~size_t(255);
        return p;
    };
    // all buffers fully written on-device every call -> no memsets needed
    int* emin = (int*)alloc(4);
    int* bmin = (int*)alloc(BIN_NB * 4);
    float* pooled = (float*)alloc((size_t)N_GRAPHS * HID * N_LAYER * 4);  // zeroed by k_base
    int* hist = (int*)alloc((size_t)BIN_NB * NBKT * 4);
    int* colex = (int*)alloc((size_t)BIN_NB * NBKT * 4);
    int* btot = (int*)alloc(NBKT * 4);
    int* rp = (int*)alloc((N_NODES + 1) * 4);
    float* invd = (float*)alloc(N_NODES * 4);
    float* counts = (float*)alloc(N_GRAPHS * 4);
    unsigned* ebuf = (unsigned*)alloc((size_t)N_EDGES * 4);
    int* csr = (int*)alloc((size_t)N_EDGES * 4);
    unsigned* wlh = (unsigned*)alloc((size_t)N_LAYER * HID * 64 * 4);
    unsigned* wrh = (unsigned*)alloc((size_t)N_LAYER * HID * 64 * 4);
    unsigned* aggb = (unsigned*)alloc((size_t)N_NODES * 64 * 4);   // bf16x2 packed
    unsigned* xb = (unsigned*)alloc((size_t)N_NODES * 64 * 4);
    unsigned* hb1 = (unsigned*)alloc((size_t)N_NODES * 64 * 4);
    unsigned* hb2 = (unsigned*)alloc((size_t)N_NODES * 64 * 4);

    k_minh<<<BIN_NB, 512, 0, stream>>>(ei, x, Wl, Wr, bmin, hist, xb, wlh, wrh);
    k_base<<<NBKT, BIN_NB, 0, stream>>>(hist, colex, btot, pooled, bmin, emin, batch, counts);
    k_bin<<<BIN_NB, 512, 0, stream>>>(ei, emin, btot, colex, ebuf);
    k_scatter2<<<NBKT + 1, 512, 0, stream>>>(ebuf, btot, emin, rp, invd, csr);

    const unsigned* hin = xb;
    unsigned* houts[3] = {hb1, hb2, hb1};
    for (int layer = 0; layer < N_LAYER; ++layer) {
        k_agg<<<N_NODES, 64, 0, stream>>>(hin, rp, csr, invd, aggb);
        k_gemm<<<(N_NODES + 63) / 64, 256, 0, stream>>>(
            aggb, hin,
            wlh + (size_t)layer * HID * 64, wrh + (size_t)layer * HID * 64,
            bl + (size_t)layer * HID, batch, houts[layer], pooled, layer,
            layer < N_LAYER - 1 ? 1 : 0);
        hin = houts[layer];
    }
    k_fc<<<N_GRAPHS, 256, 0, stream>>>(pooled, counts, fc1w, fc1b, fc2w, fc2b, out);
}